// Round 2
// baseline (274.146 us; speedup 1.0000x reference)
//
#include <hip/hip_runtime.h>

#define KTOT 65536
#define QN 16
#define DN 64
#define BN 8
#define TILE 256

// smem layout (floats)
#define QS_OFF 0                    // q scaled: [16][64]             = 1024
#define KT_OFF 1024                 // K half-tile swizzled [256][32] = 8192  (reused for U-reduce)
#define A_OFF  9216                 // attn tile [16][256]            = 4096  (reused for nacc-reduce)
#define SMEM_FLOATS 13312           // 53,248 B -> 3 blocks/CU

// ---------------- Fused: QK^T + softmax(Q) + attn write + PV partials + norm partials ----------------
__global__ __launch_bounds__(256, 3) void fused_attn(
    const float* __restrict__ query, const float* __restrict__ key,
    const float* __restrict__ value, float* __restrict__ attn,
    float* __restrict__ normp, float* __restrict__ upart,
    int NCH, int ntiles)
{
    __shared__ float smem[SMEM_FLOATS];
    const int b    = blockIdx.y;
    const int c    = blockIdx.x;
    const int tid  = threadIdx.x;
    const int wv   = tid >> 6;
    const int lane = tid & 63;

    const int chunk = ntiles * TILE;

    // ---- issue K-half0 loads for tile 0 FIRST (max time in flight) ----
    float4 stg[8];
    {
        const float4* kb = reinterpret_cast<const float4*>(
            key + ((size_t)b * KTOT + c * chunk) * DN);
        #pragma unroll
        for (int j = 0; j < 8; ++j) {
            const int o = j * 256 + tid, r = o >> 3, cc = o & 7;
            stg[j] = kb[r * 16 + cc];
        }
    }
    // Q -> LDS, pre-scaled by 1/sqrt(64)
    {
        float4 qv = reinterpret_cast<const float4*>(query + (size_t)b * QN * DN)[tid];
        qv.x *= 0.125f; qv.y *= 0.125f; qv.z *= 0.125f; qv.w *= 0.125f;
        reinterpret_cast<float4*>(&smem[QS_OFF])[tid] = qv;
    }

    float U[QN], nacc[QN];
    #pragma unroll
    for (int q = 0; q < QN; ++q) { U[q] = 0.f; nacc[q] = 0.f; }

    for (int t = 0; t < ntiles; ++t) {
        const int krow0 = c * chunk + t * TILE;
        const float4* kbase = reinterpret_cast<const float4*>(
            key + ((size_t)b * KTOT + krow0) * DN);

        // ---- write K-half0 (stg preloaded; KT's last reader was before the pre-PV barrier) ----
        #pragma unroll
        for (int j = 0; j < 8; ++j) {
            const int o = j * 256 + tid, r = o >> 3, cc = o & 7;
            *reinterpret_cast<float4*>(&smem[KT_OFF + r * 32 + ((cc ^ (r & 7)) << 2)]) = stg[j];
        }
        __syncthreads();                                        // (b) half0 visible

        // issue K-half1 loads: ride through dot0
        #pragma unroll
        for (int j = 0; j < 8; ++j) {
            const int o = j * 256 + tid, r = o >> 3, cc = o & 7;
            stg[j] = kbase[r * 16 + 8 + cc];
        }

        float s[QN];
        #pragma unroll
        for (int q = 0; q < QN; ++q) s[q] = 0.f;

        // ---- dot, d-half 0 ----
        #pragma unroll
        for (int i = 0; i < 8; ++i) {
            const float4 kv = *reinterpret_cast<const float4*>(
                &smem[KT_OFF + tid * 32 + ((i ^ (tid & 7)) << 2)]);
            #pragma unroll
            for (int q = 0; q < QN; ++q) {
                const float4 qv = *reinterpret_cast<const float4*>(
                    &smem[QS_OFF + q * DN + i * 4]);
                s[q] = fmaf(kv.x, qv.x, s[q]);
                s[q] = fmaf(kv.y, qv.y, s[q]);
                s[q] = fmaf(kv.z, qv.z, s[q]);
                s[q] = fmaf(kv.w, qv.w, s[q]);
            }
        }
        __syncthreads();                                        // (c) readers of half0 done
        #pragma unroll
        for (int j = 0; j < 8; ++j) {
            const int o = j * 256 + tid, r = o >> 3, cc = o & 7;
            *reinterpret_cast<float4*>(&smem[KT_OFF + r * 32 + ((cc ^ (r & 7)) << 2)]) = stg[j];
        }
        __syncthreads();                                        // (d) half1 visible

        // ---- issue V prefetch, first 32 rows of this wave: rides through dot1+softmax ----
        const float* vrow = value + ((size_t)b * KTOT + krow0 + wv * 64) * DN + lane;
        float vpre[32];
        #pragma unroll
        for (int i = 0; i < 32; ++i) vpre[i] = vrow[(size_t)i * DN];

        // ---- dot, d-half 1 ----
        #pragma unroll
        for (int i = 0; i < 8; ++i) {
            const float4 kv = *reinterpret_cast<const float4*>(
                &smem[KT_OFF + tid * 32 + ((i ^ (tid & 7)) << 2)]);
            #pragma unroll
            for (int q = 0; q < QN; ++q) {
                const float4 qv = *reinterpret_cast<const float4*>(
                    &smem[QS_OFF + q * DN + 32 + i * 4]);
                s[q] = fmaf(kv.x, qv.x, s[q]);
                s[q] = fmaf(kv.y, qv.y, s[q]);
                s[q] = fmaf(kv.z, qv.z, s[q]);
                s[q] = fmaf(kv.w, qv.w, s[q]);
            }
        }

        // ---- softmax over the 16 queries (thread-local) ----
        float m = s[0];
        #pragma unroll
        for (int q = 1; q < QN; ++q) m = fmaxf(m, s[q]);
        float e[QN], sum = 0.f;
        #pragma unroll
        for (int q = 0; q < QN; ++q) { e[q] = __expf(s[q] - m); sum += e[q]; }
        const float inv = 1.0f / sum;
        float a_r[QN];
        #pragma unroll
        for (int q = 0; q < QN; ++q) {
            a_r[q] = e[q] * inv;
            smem[A_OFF + q * TILE + tid] = a_r[q];              // LDS copy for PV
            nacc[q] += a_r[q];
        }
        __syncthreads();                                        // (e) A visible (drains vpre only)

        // ---- post-barrier issues: everything below rides through the barrier-free PV ----
        // attn global store (deferred, nontemporal: write-once stream, keep L2/L3 for K/V)
        {
            float* ab = attn + (size_t)b * QN * KTOT + krow0 + tid;
            #pragma unroll
            for (int q = 0; q < QN; ++q)
                __builtin_nontemporal_store(a_r[q], ab + (size_t)q * KTOT);
        }
        // V second half
        float v2[32];
        #pragma unroll
        for (int i = 0; i < 32; ++i) v2[i] = vrow[(size_t)(32 + i) * DN];
        // next tile's K-half0
        if (t + 1 < ntiles) {
            const float4* kb2 = kbase + TILE * 16;
            #pragma unroll
            for (int j = 0; j < 8; ++j) {
                const int o = j * 256 + tid, r = o >> 3, cc = o & 7;
                stg[j] = kb2[r * 16 + cc];
            }
        }

        // ---- PV: U[q][lane=d] += a[q][k] * v[k][d]; wave owns 64 k-rows ----
        const int kl0 = wv * 64;
        #pragma unroll
        for (int kk = 0; kk < 32; kk += 4) {
            #pragma unroll
            for (int qh = 0; qh < 2; ++qh) {
                float4 av[8];
                #pragma unroll
                for (int q = 0; q < 8; ++q)
                    av[q] = *reinterpret_cast<const float4*>(
                        &smem[A_OFF + (qh * 8 + q) * TILE + kl0 + kk]);
                #pragma unroll
                for (int q = 0; q < 8; ++q) {
                    U[qh * 8 + q] = fmaf(av[q].x, vpre[kk + 0], U[qh * 8 + q]);
                    U[qh * 8 + q] = fmaf(av[q].y, vpre[kk + 1], U[qh * 8 + q]);
                    U[qh * 8 + q] = fmaf(av[q].z, vpre[kk + 2], U[qh * 8 + q]);
                    U[qh * 8 + q] = fmaf(av[q].w, vpre[kk + 3], U[qh * 8 + q]);
                }
            }
        }
        #pragma unroll
        for (int kk = 32; kk < 64; kk += 4) {
            #pragma unroll
            for (int qh = 0; qh < 2; ++qh) {
                float4 av[8];
                #pragma unroll
                for (int q = 0; q < 8; ++q)
                    av[q] = *reinterpret_cast<const float4*>(
                        &smem[A_OFF + (qh * 8 + q) * TILE + kl0 + kk]);
                #pragma unroll
                for (int q = 0; q < 8; ++q) {
                    U[qh * 8 + q] = fmaf(av[q].x, v2[kk - 32 + 0], U[qh * 8 + q]);
                    U[qh * 8 + q] = fmaf(av[q].y, v2[kk - 32 + 1], U[qh * 8 + q]);
                    U[qh * 8 + q] = fmaf(av[q].z, v2[kk - 32 + 2], U[qh * 8 + q]);
                    U[qh * 8 + q] = fmaf(av[q].w, v2[kk - 32 + 3], U[qh * 8 + q]);
                }
            }
        }
    }

    // ---- block reductions: U across 4 waves (KT region), nacc across 256 threads (A region) ----
    __syncthreads();
    #pragma unroll
    for (int q = 0; q < QN; ++q)
        smem[KT_OFF + (wv * QN + q) * DN + lane] = U[q];
    #pragma unroll
    for (int q = 0; q < QN; ++q) {
        #pragma unroll
        for (int off = 1; off < 64; off <<= 1)
            nacc[q] += __shfl_xor(nacc[q], off, 64);
    }
    if (lane == 0) {
        #pragma unroll
        for (int q = 0; q < QN; ++q) smem[A_OFF + wv * QN + q] = nacc[q];
    }
    __syncthreads();

    {
        const int q = tid >> 4, d0 = (tid & 15) * 4;
        const float4 r0 = *reinterpret_cast<const float4*>(&smem[KT_OFF + (0 * QN + q) * DN + d0]);
        const float4 r1 = *reinterpret_cast<const float4*>(&smem[KT_OFF + (1 * QN + q) * DN + d0]);
        const float4 r2 = *reinterpret_cast<const float4*>(&smem[KT_OFF + (2 * QN + q) * DN + d0]);
        const float4 r3 = *reinterpret_cast<const float4*>(&smem[KT_OFF + (3 * QN + q) * DN + d0]);
        float4 rs;
        rs.x = r0.x + r1.x + r2.x + r3.x;
        rs.y = r0.y + r1.y + r2.y + r3.y;
        rs.z = r0.z + r1.z + r2.z + r3.z;
        rs.w = r0.w + r1.w + r2.w + r3.w;
        *reinterpret_cast<float4*>(
            &upart[(((size_t)b * NCH + c) * QN + q) * DN + d0]) = rs;
        if (tid < QN)
            normp[((size_t)b * NCH + c) * QN + tid] =
                smem[A_OFF + tid] + smem[A_OFF + QN + tid] +
                smem[A_OFF + 2 * QN + tid] + smem[A_OFF + 3 * QN + tid];
    }
}

// ---------------- Finalize: out[b][q][d] = sum_c U / (sum_c norm + eps); grid (8,16) ----------------
__global__ __launch_bounds__(256) void k3_fin(
    const float* __restrict__ upart, const float* __restrict__ normp,
    float* __restrict__ out, int NCH)
{
    const int b = blockIdx.x, q = blockIdx.y;
    const int tid = threadIdx.x;
    const int wv = tid >> 6, lane = tid & 63;

    float nv = 0.f;
    for (int c = tid; c < NCH; c += 256)
        nv += normp[((size_t)b * NCH + c) * QN + q];
    #pragma unroll
    for (int off = 1; off < 64; off <<= 1) nv += __shfl_xor(nv, off, 64);
    __shared__ float nred[4];
    if (lane == 0) nred[wv] = nv;

    float acc = 0.f;
    for (int c = wv; c < NCH; c += 4)
        acc += upart[(((size_t)b * NCH + c) * QN + q) * DN + lane];
    __shared__ float ured[4][DN];
    ured[wv][lane] = acc;
    __syncthreads();

    if (tid < DN) {
        const float n   = nred[0] + nred[1] + nred[2] + nred[3];
        const float inv = 1.0f / (n + 1e-8f);
        const float u   = ured[0][tid] + ured[1][tid] + ured[2][tid] + ured[3][tid];
        out[((size_t)b * QN + q) * DN + tid] = u * inv;
    }
}

extern "C" void kernel_launch(void* const* d_in, const int* in_sizes, int n_in,
                              void* d_out, int out_size, void* d_ws, size_t ws_size,
                              hipStream_t stream)
{
    const float* query = (const float*)d_in[0];
    const float* key   = (const float*)d_in[1];
    const float* value = (const float*)d_in[2];

    float* out  = (float*)d_out;                          // [8,16,64]
    float* attn = (float*)d_out + (size_t)BN * QN * DN;   // [8,1,16,65536]

    int NCH = 128;                                        // chunks per batch; ntiles = 2
    while (NCH > 8 && (size_t)NCH * BN * QN * (DN + 1) * 4 > ws_size) NCH >>= 1;
    const int ntiles = (KTOT / NCH) / TILE;

    float* normp = (float*)d_ws;                          // [8][NCH][16]
    float* upart = (float*)d_ws + (size_t)NCH * BN * QN;  // [8][NCH][16][64]

    fused_attn<<<dim3(NCH, BN), 256, 0, stream>>>(query, key, value, attn,
                                                  normp, upart, NCH, ntiles);
    k3_fin   <<<dim3(BN, QN), 256, 0, stream>>>(upart, normp, out, NCH);
}

// Round 3
// 109.519 us; speedup vs baseline: 2.5032x; 2.5032x over previous
//
#include <hip/hip_runtime.h>

#define KTOT 65536
#define QN 16
#define DN 64
#define BN 8
#define TILE 256

// smem layout (floats)
#define QS_OFF 0                    // Q scaled: [16][64]                 = 1024 floats
#define R0_OFF 1024                 // K quarter region 0: [256][16]      = 4096
#define R1_OFF 5120                 // K quarter region 1: [256][16]      = 4096
#define A_OFF  9216                 // attn tile [16][256]                = 4096
#define SMEM_FLOATS 13312           // 53,248 B -> 3 blocks/CU

// async global->LDS, 16B per lane; LDS dest linear (wave-uniform base + lane*16)
__device__ __forceinline__ void gload_lds16(const float* g, float* l)
{
    __builtin_amdgcn_global_load_lds(
        (const __attribute__((address_space(1))) void*)g,
        (__attribute__((address_space(3))) void*)l, 16, 0, 0);
}

// Stage one K quarter (16KB: 256 rows x 4 float4) into region RX.
// Source is PRE-SWIZZLED so that LDS slot s=(r,p) holds global col (p ^ ((r>>1)&3));
// read side applies the same XOR -> bank-conflict-free b128 reads (8-phase floor).
#define STAGE_QUARTER(RX, kb4, qo4)                                          \
    {                                                                        \
        _Pragma("unroll")                                                    \
        for (int j = 0; j < 4; ++j) {                                        \
            const int s_ = j * 256 + tid;                                    \
            const int r_ = s_ >> 2, p_ = s_ & 3;                             \
            const int f_ = (r_ >> 1) & 3;                                    \
            gload_lds16((const float*)((kb4) + r_ * 16 + (qo4) + (p_ ^ f_)), \
                        (float*)(((float4*)&smem[RX]) + s_));                \
        }                                                                    \
    }

// ---------------- Fused: QK^T + softmax(Q) + attn write + PV partials + norm partials ----------------
__global__ __launch_bounds__(256, 3) void fused_attn(
    const float* __restrict__ query, const float* __restrict__ key,
    const float* __restrict__ value, float* __restrict__ attn,
    float* __restrict__ normp, float* __restrict__ upart,
    int NCH, int ntiles)
{
    __shared__ float smem[SMEM_FLOATS];
    const int b    = blockIdx.y;
    const int c    = blockIdx.x;
    const int tid  = threadIdx.x;
    const int wv   = tid >> 6;
    const int lane = tid & 63;
    const int chunk = ntiles * TILE;

    // ---- prologue: issue tile0/quarter0 ASAP (async, no regs), then Q -> LDS ----
    {
        const float4* kb4 = reinterpret_cast<const float4*>(
            key + ((size_t)b * KTOT + c * chunk) * DN);
        STAGE_QUARTER(R0_OFF, kb4, 0);
    }
    {
        float4 qv = reinterpret_cast<const float4*>(query + (size_t)b * QN * DN)[tid];
        qv.x *= 0.125f; qv.y *= 0.125f; qv.z *= 0.125f; qv.w *= 0.125f;
        reinterpret_cast<float4*>(&smem[QS_OFF])[tid] = qv;
    }

    float U[QN], nacc[QN];
    #pragma unroll
    for (int q = 0; q < QN; ++q) { U[q] = 0.f; nacc[q] = 0.f; }

    const int fr = (tid >> 1) & 3;          // read-side swizzle for row tid

    for (int t = 0; t < ntiles; ++t) {
        const int krow0 = c * chunk + t * TILE;
        const float4* kb4 = reinterpret_cast<const float4*>(
            key + ((size_t)b * KTOT + krow0) * DN);

        float s[QN];
        #pragma unroll
        for (int q = 0; q < QN; ++q) s[q] = 0.f;

        // ---- 4 pipelined dot quarters: barrier drains the in-flight quarter,
        //      next quarter's loads are issued immediately and ride through the dot ----
        #pragma unroll
        for (int qt = 0; qt < 4; ++qt) {
            __syncthreads();                              // quarter qt visible in R[qt&1]
            if (qt < 3) {
                if (qt & 1) { STAGE_QUARTER(R0_OFF, kb4, (qt + 1) * 4); }
                else        { STAGE_QUARTER(R1_OFF, kb4, (qt + 1) * 4); }
            }
            const int RX = (qt & 1) ? R1_OFF : R0_OFF;
            #pragma unroll
            for (int cc = 0; cc < 4; ++cc) {
                const float4 kv = ((const float4*)&smem[RX])[tid * 4 + (cc ^ fr)];
                #pragma unroll
                for (int q = 0; q < QN; ++q) {
                    const float4 qv = *reinterpret_cast<const float4*>(
                        &smem[QS_OFF + q * DN + qt * 16 + cc * 4]);   // uniform broadcast
                    s[q] = fmaf(kv.x, qv.x, s[q]);
                    s[q] = fmaf(kv.y, qv.y, s[q]);
                    s[q] = fmaf(kv.z, qv.z, s[q]);
                    s[q] = fmaf(kv.w, qv.w, s[q]);
                }
            }
        }

        // ---- softmax over the 16 queries (thread-local, k = krow0+tid) ----
        float m = s[0];
        #pragma unroll
        for (int q = 1; q < QN; ++q) m = fmaxf(m, s[q]);
        float sum = 0.f;
        #pragma unroll
        for (int q = 0; q < QN; ++q) { s[q] = __expf(s[q] - m); sum += s[q]; }
        const float inv = 1.0f / sum;
        {
            float* ab = attn + (size_t)b * QN * KTOT + krow0 + tid;
            #pragma unroll
            for (int q = 0; q < QN; ++q) {
                const float a = s[q] * inv;
                __builtin_nontemporal_store(a, ab + (size_t)q * KTOT);  // write-once stream
                smem[A_OFF + q * TILE + tid] = a;                       // consecutive lanes -> free
                nacc[q] += a;
            }
        }
        __syncthreads();                                  // A visible

        // next tile's quarter 0: rides through the whole (barrier-free) PV phase
        if (t + 1 < ntiles) { STAGE_QUARTER(R0_OFF, kb4 + TILE * 16, 0); }

        // ---- PV: U[q][lane=d] += a[q][k] * v[k][d]; wave owns 64 k-rows ----
        const int kl0 = wv * 64;
        const float* vptr = value + ((size_t)b * KTOT + krow0 + kl0) * DN + lane;
        float va[8];
        #pragma unroll
        for (int i = 0; i < 8; ++i) va[i] = vptr[(size_t)i * DN];   // 256B/instr coalesced
        #pragma unroll 1
        for (int kk = 0; kk < 64; kk += 8) {
            float vb[8];
            const int nxt = kk + 8;
            if (nxt < 64) {
                #pragma unroll
                for (int i = 0; i < 8; ++i) vb[i] = vptr[(size_t)(nxt + i) * DN];
            }
            #pragma unroll
            for (int kq = 0; kq < 8; kq += 4) {
                #pragma unroll
                for (int q = 0; q < QN; ++q) {
                    const float4 av = *reinterpret_cast<const float4*>(
                        &smem[A_OFF + q * TILE + kl0 + kk + kq]);   // uniform broadcast
                    U[q] = fmaf(av.x, va[kq + 0], U[q]);
                    U[q] = fmaf(av.y, va[kq + 1], U[q]);
                    U[q] = fmaf(av.z, va[kq + 2], U[q]);
                    U[q] = fmaf(av.w, va[kq + 3], U[q]);
                }
            }
            #pragma unroll
            for (int i = 0; i < 8; ++i) va[i] = vb[i];
        }
    }

    // ---- block reductions: U across 4 waves (R0/R1 regions), nacc (A region) ----
    __syncthreads();
    #pragma unroll
    for (int q = 0; q < QN; ++q)
        smem[R0_OFF + (wv * QN + q) * DN + lane] = U[q];
    #pragma unroll
    for (int q = 0; q < QN; ++q) {
        #pragma unroll
        for (int off = 1; off < 64; off <<= 1)
            nacc[q] += __shfl_xor(nacc[q], off, 64);
    }
    if (lane == 0) {
        #pragma unroll
        for (int q = 0; q < QN; ++q) smem[A_OFF + wv * QN + q] = nacc[q];
    }
    __syncthreads();

    {
        const int q = tid >> 4, d0 = (tid & 15) * 4;
        const float4 r0 = *reinterpret_cast<const float4*>(&smem[R0_OFF + (0 * QN + q) * DN + d0]);
        const float4 r1 = *reinterpret_cast<const float4*>(&smem[R0_OFF + (1 * QN + q) * DN + d0]);
        const float4 r2 = *reinterpret_cast<const float4*>(&smem[R0_OFF + (2 * QN + q) * DN + d0]);
        const float4 r3 = *reinterpret_cast<const float4*>(&smem[R0_OFF + (3 * QN + q) * DN + d0]);
        float4 rs;
        rs.x = r0.x + r1.x + r2.x + r3.x;
        rs.y = r0.y + r1.y + r2.y + r3.y;
        rs.z = r0.z + r1.z + r2.z + r3.z;
        rs.w = r0.w + r1.w + r2.w + r3.w;
        *reinterpret_cast<float4*>(
            &upart[(((size_t)b * NCH + c) * QN + q) * DN + d0]) = rs;
        if (tid < QN)
            normp[((size_t)b * NCH + c) * QN + tid] =
                smem[A_OFF + tid] + smem[A_OFF + QN + tid] +
                smem[A_OFF + 2 * QN + tid] + smem[A_OFF + 3 * QN + tid];
    }
}

// ---------------- Finalize: out[b][q][d] = sum_c U / (sum_c norm + eps); grid (8,16) ----------------
__global__ __launch_bounds__(256) void k3_fin(
    const float* __restrict__ upart, const float* __restrict__ normp,
    float* __restrict__ out, int NCH)
{
    const int b = blockIdx.x, q = blockIdx.y;
    const int tid = threadIdx.x;
    const int wv = tid >> 6, lane = tid & 63;

    float nv = 0.f;
    for (int c = tid; c < NCH; c += 256)
        nv += normp[((size_t)b * NCH + c) * QN + q];
    #pragma unroll
    for (int off = 1; off < 64; off <<= 1) nv += __shfl_xor(nv, off, 64);
    __shared__ float nred[4];
    if (lane == 0) nred[wv] = nv;

    float acc = 0.f;
    for (int c = wv; c < NCH; c += 4)
        acc += upart[(((size_t)b * NCH + c) * QN + q) * DN + lane];
    __shared__ float ured[4][DN];
    ured[wv][lane] = acc;
    __syncthreads();

    if (tid < DN) {
        const float n   = nred[0] + nred[1] + nred[2] + nred[3];
        const float inv = 1.0f / (n + 1e-8f);
        const float u   = ured[0][tid] + ured[1][tid] + ured[2][tid] + ured[3][tid];
        out[((size_t)b * QN + q) * DN + tid] = u * inv;
    }
}

extern "C" void kernel_launch(void* const* d_in, const int* in_sizes, int n_in,
                              void* d_out, int out_size, void* d_ws, size_t ws_size,
                              hipStream_t stream)
{
    const float* query = (const float*)d_in[0];
    const float* key   = (const float*)d_in[1];
    const float* value = (const float*)d_in[2];

    float* out  = (float*)d_out;                          // [8,16,64]
    float* attn = (float*)d_out + (size_t)BN * QN * DN;   // [8,1,16,65536]

    int NCH = 128;                                        // chunks per batch; ntiles = 2
    while (NCH > 8 && (size_t)BN * NCH * QN * (DN + 1) * 4 > ws_size) NCH >>= 1;
    const int ntiles = (KTOT / NCH) / TILE;

    float* normp = (float*)d_ws;                          // [8][NCH][16]
    float* upart = (float*)d_ws + (size_t)BN * NCH * QN;  // [8][NCH][16][64]

    fused_attn<<<dim3(NCH, BN), 256, 0, stream>>>(query, key, value, attn,
                                                  normp, upart, NCH, ntiles);
    k3_fin   <<<dim3(BN, QN), 256, 0, stream>>>(upart, normp, out, NCH);
}